// Round 8
// baseline (49.433 us; speedup 1.0000x reference)
//
#include <hip/hip_runtime.h>
#include <math.h>

// B=4, C=64, H=W=128, OUTC=64, KS=3, taps N=9, K = 9*64 = 576. All fp16 data, f32 accum.
// ws layout (bytes):
//   x_t   fp16 [4][128][128][64]   @ 0        (8 MB) NHWC
//   cwtf  fp16 [9][2][4][64][8]    @ 8388608  (72 KB) main-conv B-fragments
//   pwtf  fp16 [9][2][2][64][8]    @ 8462336  (36 KB) offset-conv B-fragments (rows>=18 zero)
//   zpad  fp16 [64]                @ 8499200  (128 B) zero page for OOB DMA
#define CWTF_OFF 8388608
#define PWTF_OFF (CWTF_OFF + 73728)
#define ZPAD_OFF (PWTF_OFF + 36864)

typedef __attribute__((ext_vector_type(8))) _Float16 half8;
typedef __attribute__((ext_vector_type(8))) unsigned short ushort8;
typedef __attribute__((ext_vector_type(4))) float f32x4;
typedef __attribute__((ext_vector_type(4))) unsigned int u32x4;

__device__ inline unsigned short f2h(float f) {
    _Float16 h = (_Float16)f; return __builtin_bit_cast(unsigned short, h);
}

__device__ inline void gload_lds16(const unsigned short* g, void* l) {
    __builtin_amdgcn_global_load_lds(
        (const __attribute__((address_space(1))) void*)g,
        (__attribute__((address_space(3))) void*)l, 16, 0, 0);
}

// ---------------- prep: x NCHW f32 -> NHWC fp16, weights -> fragment order, zero page ----------------
__global__ __launch_bounds__(256) void k_prep(const float* __restrict__ x,
                                              unsigned int* __restrict__ x_t_u32,
                                              const float* __restrict__ conv_w,
                                              const float* __restrict__ p_w,
                                              unsigned short* __restrict__ cwtf,
                                              unsigned short* __restrict__ pwtf,
                                              unsigned short* __restrict__ zpad) {
    if (blockIdx.x < 512) {
        __shared__ float t[64][129];
        int b = blockIdx.x >> 7;
        int i = blockIdx.x & 127;
        for (int idx = threadIdx.x; idx < 64 * 128; idx += 256) {
            int c = idx >> 7, j = idx & 127;
            t[c][j] = x[(((size_t)(b * 64 + c) * 128 + i) << 7) + j];
        }
        __syncthreads();
        unsigned int* dst = x_t_u32 + ((size_t)(b * 128 + i)) * 128 * 32;
        for (int idx2 = threadIdx.x; idx2 < 4096; idx2 += 256) {
            int j = idx2 >> 5, c2 = idx2 & 31;
            unsigned int lo = f2h(t[2 * c2][j]);
            unsigned int hi = f2h(t[2 * c2 + 1][j]);
            dst[idx2] = lo | (hi << 16);
        }
    } else {
        int tid = (blockIdx.x - 512) * 256 + threadIdx.x;
        if (tid < 36864) {
            int e = tid & 7, lane = (tid >> 3) & 63, nb = (tid >> 9) & 3, h = (tid >> 11) & 1, n = tid >> 12;
            int o = nb * 16 + (lane & 15);
            int c = h * 32 + ((lane >> 4) << 3) + e;
            cwtf[tid] = f2h(conv_w[(o * 64 + c) * 9 + n]);
        } else if (tid < 36864 + 18432) {
            int t2 = tid - 36864;
            int e = t2 & 7, lane = (t2 >> 3) & 63, nb = (t2 >> 9) & 1, h = (t2 >> 10) & 1, n = t2 >> 11;
            int np = nb * 16 + (lane & 15);
            int c = h * 32 + ((lane >> 4) << 3) + e;
            pwtf[t2] = (np < 18) ? f2h(p_w[(np * 64 + c) * 9 + n]) : (unsigned short)0;
        } else if (tid < 36864 + 18432 + 64) {
            zpad[tid - 55296] = 0;
        }
    }
}

// ---------------- fused kernel ----------------
// Block = 64 pixels (b, i, j0..j0+63), 8 waves (512 thr): wave wv = (pg = wv&3, h = wv>>2).
// Tile margin 2 (covers |offset| < 1; rare exceedances take per-corner global path).
// MFMA 16x16x32 f16: A m=lane&15, k=8*(lane>>4)+e; B n=lane&15 same k; D n=lane&15, m=4*(lane>>4)+reg.
#define TROWS 5
#define TCOLS 68
#define TRECS (TROWS * TCOLS)      // 340 records of 128 B (64 ch fp16)
#define TILE_B (TRECS * 128)       // 43520 B
#define NWORDS (TRECS * 8)         // 2720 16B words
// LDS: tile [0, 43520) ; offs [64][18] f32 overlaid by geom [9][64][4] u32 at TILE_B (9216 B)
// epilogue: ep0 @0, ep1 @16640 ([64][65] f32 each) overlaying dead tile.

__global__ __launch_bounds__(512, 6) void k_fused(const unsigned short* __restrict__ x_t,
                                                  const unsigned short* __restrict__ cwtf,
                                                  const unsigned short* __restrict__ pwtf,
                                                  const float* __restrict__ p_b,
                                                  const float* __restrict__ conv_b,
                                                  const unsigned short* __restrict__ zpad,
                                                  float* __restrict__ out) {
    __shared__ __align__(16) unsigned char S[TILE_B + 9216];
    unsigned char* tile = S;
    float* offs = (float*)(S + TILE_B);
    unsigned char* geomB = S + TILE_B;  // overlays offs (offs dead after phase 2 stage A)

    int bid0 = blockIdx.x;
    int bid = (bid0 & 7) * 128 + (bid0 >> 3);  // chunked XCD swizzle (1024 % 8 == 0)
    int b = bid >> 8;
    int i = (bid >> 1) & 127;
    int j0 = (bid & 1) << 6;
    int ib = i - 2, jb = j0 - 2;

    int tid = threadIdx.x;
    int lane = tid & 63;
    int r15 = lane & 15;
    int g = lane >> 4;
    int wv = tid >> 6;
    int pg = wv & 3;
    int h = wv >> 2;
    int pl = pg * 16 + r15;      // this lane's A-row pixel
    int cs = g + (h << 2);       // chunk slot: channels cs*8..cs*8+7
    int csx = cs << 4;

    // ---- stage tile via global_load_lds: linear LDS dest, pre-swizzled global source ----
#pragma unroll
    for (int it = 0; it < 6; ++it) {
        int w = it * 512 + tid;
        if (w < NWORDS) {
            int rec = w >> 3, slot = w & 7;
            int trow = rec / TCOLS;
            int tcol = rec - trow * TCOLS;
            int gr = ib + trow, gc = jb + tcol;
            bool v = ((unsigned)gr < 128u) && ((unsigned)gc < 128u);
            const unsigned short* src = v
                ? x_t + (((size_t)((b * 128 + gr) * 128 + gc)) << 6) + ((slot ^ (rec & 7)) << 3)
                : zpad;
            gload_lds16(src, tile + ((it * 512 + (tid & ~63)) << 4));
        }
    }
    // init offs with bias (disjoint from tile region)
    for (int t = tid; t < 64 * 18; t += 512) {
        int np = t - (t / 18) * 18;
        offs[t] = p_b[np];
    }
    __syncthreads();

    // ---- phase 1: offset conv — wave supplies its channel-half's k-block, ds_add reduce ----
    {
        f32x4 aco0 = (f32x4)0.f, aco1 = (f32x4)0.f;
        for (int n = 0; n < 9; ++n) {
            int du = n / 3 - 1, dv = n % 3 - 1;
            int trec = (du + 2) * TCOLS + (pl + dv + 2);
            half8 a = *(const half8*)(tile + trec * 128 + ((((unsigned)trec & 7u) << 4) ^ csx));
            const unsigned short* pb = pwtf + (((n * 2 + h) * 2) << 9) + (lane << 3);
            half8 b0 = *(const half8*)pb;
            half8 b1 = *(const half8*)(pb + 512);
            aco0 = __builtin_amdgcn_mfma_f32_16x16x32_f16(a, b0, aco0, 0, 0, 0);
            aco1 = __builtin_amdgcn_mfma_f32_16x16x32_f16(a, b1, aco1, 0, 0, 0);
        }
#pragma unroll
        for (int rr = 0; rr < 4; ++rr) {
            int pix = pg * 16 + g * 4 + rr;
            atomicAdd(&offs[pix * 18 + r15], aco0[rr]);
            if (r15 < 2) atomicAdd(&offs[pix * 18 + 16 + r15], aco1[rr]);
        }
    }
    __syncthreads();

    // ---- phase 2: bilinear geometry (reg-staged, then overlay-write over offs) ----
    // item m in [0,576): pixel p = m&63, tap n = m>>6. Entry u32:
    //   low16 = f16 weight; hi16: <0x8000 -> rec*8+(rec&7) (swizzled LDS base>>4)
    //                       >=0x8000 -> 0x8000|(rx<<7)|ry (global fallback, rare)
    u32x4 gA, gB;
#pragma unroll
    for (int pass = 0; pass < 2; ++pass) {
        int m = tid + pass * 512;
        if (pass == 1 && tid >= 64) break;
        int p = m & 63;
        int n = m >> 6;
        float ox = offs[p * 18 + n];
        float oy = offs[p * 18 + 9 + n];
        float px = ox + (float)(i + 1) + (float)(n / 3 - 1);
        float py = oy + (float)(j0 + p + 1) + (float)(n % 3 - 1);
        float fx = floorf(px), fy = floorf(py);
        float qlx = fminf(fmaxf(fx, 0.f), 129.f);
        float qrx = fminf(fmaxf(fx + 1.f, 0.f), 129.f);
        float qly = fminf(fmaxf(fy, 0.f), 129.f);
        float qry = fminf(fmaxf(fy + 1.f, 0.f), 129.f);
        float pxc = fminf(fmaxf(px, 0.f), 129.f);
        float pyc = fminf(fmaxf(py, 0.f), 129.f);
        float ax = 1.f + qlx - pxc;
        float bx = 1.f - qrx + pxc;
        float ay = 1.f + qly - pyc;
        float by = 1.f - qry + pyc;
        int cx[4], cy[4];
        cx[0] = (int)qlx - 1; cy[0] = (int)qly - 1;
        cx[1] = (int)qrx - 1; cy[1] = (int)qry - 1;
        cx[2] = (int)qlx - 1; cy[2] = (int)qry - 1;
        cx[3] = (int)qrx - 1; cy[3] = (int)qly - 1;
        float cw[4] = {ax * ay, bx * by, ax * by, bx * ay};
        u32x4 pk;
#pragma unroll
        for (int k = 0; k < 4; ++k) {
            bool v = ((unsigned)cx[k] < 128u) && ((unsigned)cy[k] < 128u);
            bool intile = (((unsigned)(cx[k] - ib) < (unsigned)TROWS) &&
                           ((unsigned)(cy[k] - jb) < (unsigned)TCOLS));
            unsigned rec = (unsigned)(cx[k] - ib) * TCOLS + (unsigned)(cy[k] - jb);
            unsigned hi = 0u;
            if (v) hi = intile ? (rec * 8u + (rec & 7u))
                               : (0x8000u | ((unsigned)cx[k] << 7) | (unsigned)cy[k]);
            unsigned wt = v ? (unsigned)f2h(cw[k]) : 0u;
            pk[k] = (hi << 16) | wt;
        }
        if (pass == 0) gA = pk; else gB = pk;
    }
    __syncthreads();  // all offs reads done; safe to overlay
    *(u32x4*)(geomB + (tid << 4)) = gA;
    if (tid < 64) *(u32x4*)(geomB + ((tid + 512) << 4)) = gB;
    __syncthreads();

    // ---- phase 3: main conv — slim register footprint ----
    f32x4 acc[4];
#pragma unroll
    for (int nb = 0; nb < 4; ++nb) acc[nb] = (f32x4)0.f;

    for (int n = 0; n < 9; ++n) {
        u32x4 gq = *(const u32x4*)(geomB + ((n * 64 + pl) << 4));
        half8 av = (half8)(_Float16)0;
#pragma unroll
        for (int k = 0; k < 4; ++k) {
            unsigned int p = gq[k];
            _Float16 wk = __builtin_bit_cast(_Float16, (unsigned short)(p & 0xFFFFu));
            unsigned hi = p >> 16;
            half8 u;
            if (__builtin_expect(!(hi & 0x8000u), 1)) {
                u = *(const half8*)(tile + ((hi << 4) ^ csx));
            } else {
                int rx = (int)((hi >> 7) & 127u), ry = (int)(hi & 127u);
                u = *(const half8*)(x_t + (((size_t)((b * 128 + rx) * 128 + ry)) << 6) + (cs << 3));
            }
            av += u * wk;
        }
#pragma unroll
        for (int nb = 0; nb < 4; ++nb) {
            half8 Bf = *(const half8*)(cwtf + ((((n * 2 + h) << 2) + nb) << 9) + (lane << 3));
            acc[nb] = __builtin_amdgcn_mfma_f32_16x16x32_f16(av, Bf, acc[nb], 0, 0, 0);
        }
    }
    __syncthreads();  // tile dead; reuse as ep0/ep1

    // ---- epilogue: per-half ep regions, summed at store ----
    {
        float* epH = (float*)(S + (h ? 16640 : 0));
#pragma unroll
        for (int nb = 0; nb < 4; ++nb) {
            int o = nb * 16 + r15;
#pragma unroll
            for (int rr = 0; rr < 4; ++rr) {
                int pix = pg * 16 + g * 4 + rr;
                epH[o * 65 + pix] = acc[nb][rr];
            }
        }
    }
    __syncthreads();
    {
        float* e0 = (float*)S;
        float* e1 = (float*)(S + 16640);
        for (int t = tid; t < 4096; t += 512) {
            int o = t >> 6;
            int p = t & 63;
            out[(((size_t)(b * 64 + o)) << 14) + (i << 7) + j0 + p] =
                e0[o * 65 + p] + e1[o * 65 + p] + conv_b[o];
        }
    }
}

extern "C" void kernel_launch(void* const* d_in, const int* in_sizes, int n_in,
                              void* d_out, int out_size, void* d_ws, size_t ws_size,
                              hipStream_t stream) {
    const float* x = (const float*)d_in[0];
    const float* p_w = (const float*)d_in[1];
    const float* p_b = (const float*)d_in[2];
    const float* conv_w = (const float*)d_in[3];
    const float* conv_b = (const float*)d_in[4];
    float* out = (float*)d_out;
    char* ws = (char*)d_ws;

    unsigned short* x_t = (unsigned short*)(ws);
    unsigned short* cwtf = (unsigned short*)(ws + CWTF_OFF);
    unsigned short* pwtf = (unsigned short*)(ws + PWTF_OFF);
    unsigned short* zpad = (unsigned short*)(ws + ZPAD_OFF);

    k_prep<<<729, 256, 0, stream>>>(x, (unsigned int*)x_t, conv_w, p_w, cwtf, pwtf, zpad);
    k_fused<<<1024, 512, 0, stream>>>(x_t, cwtf, pwtf, p_b, conv_b, zpad, out);
}

// Round 9
// 49.068 us; speedup vs baseline: 1.0074x; 1.0074x over previous
//
#include <hip/hip_runtime.h>
#include <math.h>

// B=4, C=64, H=W=128, OUTC=64, KS=3, taps N=9, K = 9*64 = 576. All fp16 data, f32 accum.
// ws layout (bytes):
//   x_t   fp16 [4][128][128][64]   @ 0        (8 MB) NHWC
//   cwtf  fp16 [9][2][4][64][8]    @ 8388608  (72 KB) main-conv B-fragments
//   pwtf  fp16 [9][2][2][64][8]    @ 8462336  (36 KB) offset-conv B-fragments (rows>=18 zero)
//   zpad  fp16 [64]                @ 8499200  (128 B) zero page for OOB DMA
#define CWTF_OFF 8388608
#define PWTF_OFF (CWTF_OFF + 73728)
#define ZPAD_OFF (PWTF_OFF + 36864)

typedef __attribute__((ext_vector_type(8))) _Float16 half8;
typedef __attribute__((ext_vector_type(8))) unsigned short ushort8;
typedef __attribute__((ext_vector_type(4))) float f32x4;
typedef __attribute__((ext_vector_type(4))) unsigned int u32x4;

__device__ inline unsigned short f2h(float f) {
    _Float16 h = (_Float16)f; return __builtin_bit_cast(unsigned short, h);
}

__device__ inline void gload_lds16(const unsigned short* g, void* l) {
    __builtin_amdgcn_global_load_lds(
        (const __attribute__((address_space(1))) void*)g,
        (__attribute__((address_space(3))) void*)l, 16, 0, 0);
}

// ---------------- prep: x NCHW f32 -> NHWC fp16, weights -> fragment order, zero page ----------------
__global__ __launch_bounds__(256) void k_prep(const float* __restrict__ x,
                                              unsigned int* __restrict__ x_t_u32,
                                              const float* __restrict__ conv_w,
                                              const float* __restrict__ p_w,
                                              unsigned short* __restrict__ cwtf,
                                              unsigned short* __restrict__ pwtf,
                                              unsigned short* __restrict__ zpad) {
    if (blockIdx.x < 512) {
        __shared__ float t[64][129];
        int b = blockIdx.x >> 7;
        int i = blockIdx.x & 127;
        for (int idx = threadIdx.x; idx < 64 * 128; idx += 256) {
            int c = idx >> 7, j = idx & 127;
            t[c][j] = x[(((size_t)(b * 64 + c) * 128 + i) << 7) + j];
        }
        __syncthreads();
        unsigned int* dst = x_t_u32 + ((size_t)(b * 128 + i)) * 128 * 32;
        for (int idx2 = threadIdx.x; idx2 < 4096; idx2 += 256) {
            int j = idx2 >> 5, c2 = idx2 & 31;
            unsigned int lo = f2h(t[2 * c2][j]);
            unsigned int hi = f2h(t[2 * c2 + 1][j]);
            dst[idx2] = lo | (hi << 16);
        }
    } else {
        int tid = (blockIdx.x - 512) * 256 + threadIdx.x;
        if (tid < 36864) {
            int e = tid & 7, lane = (tid >> 3) & 63, nb = (tid >> 9) & 3, h = (tid >> 11) & 1, n = tid >> 12;
            int o = nb * 16 + (lane & 15);
            int c = h * 32 + ((lane >> 4) << 3) + e;
            cwtf[tid] = f2h(conv_w[(o * 64 + c) * 9 + n]);
        } else if (tid < 36864 + 18432) {
            int t2 = tid - 36864;
            int e = t2 & 7, lane = (t2 >> 3) & 63, nb = (t2 >> 9) & 1, h = (t2 >> 10) & 1, n = t2 >> 11;
            int np = nb * 16 + (lane & 15);
            int c = h * 32 + ((lane >> 4) << 3) + e;
            pwtf[t2] = (np < 18) ? f2h(p_w[(np * 64 + c) * 9 + n]) : (unsigned short)0;
        } else if (tid < 36864 + 18432 + 64) {
            zpad[tid - 55296] = 0;
        }
    }
}

// ---------------- fused kernel ----------------
// Block = 64 pixels (b, i, j0..j0+63), 8 waves (512 thr): wave wv = (pg = wv&3, h = wv>>2).
// Tile margin 2 (covers |offset| < 1; rare exceedances take per-corner global path).
// MFMA 16x16x32 f16: A m=lane&15, k=8*(lane>>4)+e; B n=lane&15 same k; D n=lane&15, m=4*(lane>>4)+reg.
#define TROWS 5
#define TCOLS 68
#define TRECS (TROWS * TCOLS)      // 340 records of 128 B (64 ch fp16)
#define TILE_B (TRECS * 128)       // 43520 B
#define NWORDS (TRECS * 8)         // 2720 16B words
// LDS: tile [0, 43520) ; offs [64][18] f32 overlaid by geom [9][64][4] u32 at TILE_B (9216 B)
// epilogue: ep0 @0, ep1 @16640 ([64][65] f32 each) overlaying dead tile.

__global__ __launch_bounds__(512, 4) void k_fused(const unsigned short* __restrict__ x_t,
                                                  const unsigned short* __restrict__ cwtf,
                                                  const unsigned short* __restrict__ pwtf,
                                                  const float* __restrict__ p_b,
                                                  const float* __restrict__ conv_b,
                                                  const unsigned short* __restrict__ zpad,
                                                  float* __restrict__ out) {
    __shared__ __align__(16) unsigned char S[TILE_B + 9216];
    unsigned char* tile = S;
    float* offs = (float*)(S + TILE_B);
    unsigned char* geomB = S + TILE_B;  // overlays offs (offs dead after phase 2 stage A)

    int bid0 = blockIdx.x;
    int bid = (bid0 & 7) * 128 + (bid0 >> 3);  // chunked XCD swizzle (1024 % 8 == 0)
    int b = bid >> 8;
    int i = (bid >> 1) & 127;
    int j0 = (bid & 1) << 6;
    int ib = i - 2, jb = j0 - 2;

    int tid = threadIdx.x;
    int lane = tid & 63;
    int r15 = lane & 15;
    int g = lane >> 4;
    int wv = tid >> 6;
    int pg = wv & 3;
    int h = wv >> 2;
    int pl = pg * 16 + r15;      // this lane's A-row pixel
    int cs = g + (h << 2);       // chunk slot: channels cs*8..cs*8+7
    int csx = cs << 4;

    // ---- stage tile via global_load_lds: linear LDS dest, pre-swizzled global source ----
#pragma unroll
    for (int it = 0; it < 6; ++it) {
        int w = it * 512 + tid;
        if (w < NWORDS) {
            int rec = w >> 3, slot = w & 7;
            int trow = rec / TCOLS;
            int tcol = rec - trow * TCOLS;
            int gr = ib + trow, gc = jb + tcol;
            bool v = ((unsigned)gr < 128u) && ((unsigned)gc < 128u);
            const unsigned short* src = v
                ? x_t + (((size_t)((b * 128 + gr) * 128 + gc)) << 6) + ((slot ^ (rec & 7)) << 3)
                : zpad;
            gload_lds16(src, tile + ((it * 512 + (tid & ~63)) << 4));
        }
    }
    // init offs with bias (disjoint from tile region)
    for (int t = tid; t < 64 * 18; t += 512) {
        int np = t - (t / 18) * 18;
        offs[t] = p_b[np];
    }
    __syncthreads();

    // ---- phase 1: offset conv — wave supplies its channel-half's k-block, ds_add reduce ----
    {
        f32x4 aco0 = (f32x4)0.f, aco1 = (f32x4)0.f;
        for (int n = 0; n < 9; ++n) {
            int du = n / 3 - 1, dv = n % 3 - 1;
            int trec = (du + 2) * TCOLS + (pl + dv + 2);
            half8 a = *(const half8*)(tile + trec * 128 + ((((unsigned)trec & 7u) << 4) ^ csx));
            const unsigned short* pb = pwtf + (((n * 2 + h) * 2) << 9) + (lane << 3);
            half8 b0 = *(const half8*)pb;
            half8 b1 = *(const half8*)(pb + 512);
            aco0 = __builtin_amdgcn_mfma_f32_16x16x32_f16(a, b0, aco0, 0, 0, 0);
            aco1 = __builtin_amdgcn_mfma_f32_16x16x32_f16(a, b1, aco1, 0, 0, 0);
        }
#pragma unroll
        for (int rr = 0; rr < 4; ++rr) {
            int pix = pg * 16 + g * 4 + rr;
            atomicAdd(&offs[pix * 18 + r15], aco0[rr]);
            if (r15 < 2) atomicAdd(&offs[pix * 18 + 16 + r15], aco1[rr]);
        }
    }
    __syncthreads();

    // ---- phase 2: bilinear geometry (reg-staged, then overlay-write over offs) ----
    // item m in [0,576): pixel p = m&63, tap n = m>>6. Entry u32:
    //   low16 = f16 weight; hi16: <0x8000 -> rec*8+(rec&7) (swizzled LDS base>>4)
    //                       >=0x8000 -> 0x8000|(rx<<7)|ry (global fallback, rare)
    u32x4 gA, gB;
#pragma unroll
    for (int pass = 0; pass < 2; ++pass) {
        int m = tid + pass * 512;
        if (pass == 1 && tid >= 64) break;
        int p = m & 63;
        int n = m >> 6;
        float ox = offs[p * 18 + n];
        float oy = offs[p * 18 + 9 + n];
        float px = ox + (float)(i + 1) + (float)(n / 3 - 1);
        float py = oy + (float)(j0 + p + 1) + (float)(n % 3 - 1);
        float fx = floorf(px), fy = floorf(py);
        float qlx = fminf(fmaxf(fx, 0.f), 129.f);
        float qrx = fminf(fmaxf(fx + 1.f, 0.f), 129.f);
        float qly = fminf(fmaxf(fy, 0.f), 129.f);
        float qry = fminf(fmaxf(fy + 1.f, 0.f), 129.f);
        float pxc = fminf(fmaxf(px, 0.f), 129.f);
        float pyc = fminf(fmaxf(py, 0.f), 129.f);
        float ax = 1.f + qlx - pxc;
        float bx = 1.f - qrx + pxc;
        float ay = 1.f + qly - pyc;
        float by = 1.f - qry + pyc;
        int cx[4], cy[4];
        cx[0] = (int)qlx - 1; cy[0] = (int)qly - 1;
        cx[1] = (int)qrx - 1; cy[1] = (int)qry - 1;
        cx[2] = (int)qlx - 1; cy[2] = (int)qry - 1;
        cx[3] = (int)qrx - 1; cy[3] = (int)qly - 1;
        float cw[4] = {ax * ay, bx * by, ax * by, bx * ay};
        u32x4 pk;
#pragma unroll
        for (int k = 0; k < 4; ++k) {
            bool v = ((unsigned)cx[k] < 128u) && ((unsigned)cy[k] < 128u);
            bool intile = (((unsigned)(cx[k] - ib) < (unsigned)TROWS) &&
                           ((unsigned)(cy[k] - jb) < (unsigned)TCOLS));
            unsigned rec = (unsigned)(cx[k] - ib) * TCOLS + (unsigned)(cy[k] - jb);
            unsigned hi = 0u;
            if (v) hi = intile ? (rec * 8u + (rec & 7u))
                               : (0x8000u | ((unsigned)cx[k] << 7) | (unsigned)cy[k]);
            unsigned wt = v ? (unsigned)f2h(cw[k]) : 0u;
            pk[k] = (hi << 16) | wt;
        }
        if (pass == 0) gA = pk; else gB = pk;
    }
    __syncthreads();  // all offs reads done; safe to overlay
    *(u32x4*)(geomB + (tid << 4)) = gA;
    if (tid < 64) *(u32x4*)(geomB + ((tid + 512) << 4)) = gB;
    __syncthreads();

    // ---- phase 3: main conv — unroll 3, Bf batch before corner gathers ----
    f32x4 acc[4];
#pragma unroll
    for (int nb = 0; nb < 4; ++nb) acc[nb] = (f32x4)0.f;

#pragma unroll 3
    for (int n = 0; n < 9; ++n) {
        u32x4 gq = *(const u32x4*)(geomB + ((n * 64 + pl) << 4));
        half8 Bf[4];
#pragma unroll
        for (int nb = 0; nb < 4; ++nb)
            Bf[nb] = *(const half8*)(cwtf + ((((n * 2 + h) << 2) + nb) << 9) + (lane << 3));
        half8 av = (half8)(_Float16)0;
#pragma unroll
        for (int k = 0; k < 4; ++k) {
            unsigned int p = gq[k];
            _Float16 wk = __builtin_bit_cast(_Float16, (unsigned short)(p & 0xFFFFu));
            unsigned hi = p >> 16;
            half8 u;
            if (__builtin_expect(!(hi & 0x8000u), 1)) {
                u = *(const half8*)(tile + ((hi << 4) ^ csx));
            } else {
                int rx = (int)((hi >> 7) & 127u), ry = (int)(hi & 127u);
                u = *(const half8*)(x_t + (((size_t)((b * 128 + rx) * 128 + ry)) << 6) + (cs << 3));
            }
            av += u * wk;
        }
#pragma unroll
        for (int nb = 0; nb < 4; ++nb)
            acc[nb] = __builtin_amdgcn_mfma_f32_16x16x32_f16(av, Bf[nb], acc[nb], 0, 0, 0);
    }
    __syncthreads();  // tile dead; reuse as ep0/ep1

    // ---- epilogue: per-half ep regions, summed at store ----
    {
        float* epH = (float*)(S + (h ? 16640 : 0));
#pragma unroll
        for (int nb = 0; nb < 4; ++nb) {
            int o = nb * 16 + r15;
#pragma unroll
            for (int rr = 0; rr < 4; ++rr) {
                int pix = pg * 16 + g * 4 + rr;
                epH[o * 65 + pix] = acc[nb][rr];
            }
        }
    }
    __syncthreads();
    {
        float* e0 = (float*)S;
        float* e1 = (float*)(S + 16640);
        for (int t = tid; t < 4096; t += 512) {
            int o = t >> 6;
            int p = t & 63;
            out[(((size_t)(b * 64 + o)) << 14) + (i << 7) + j0 + p] =
                e0[o * 65 + p] + e1[o * 65 + p] + conv_b[o];
        }
    }
}

extern "C" void kernel_launch(void* const* d_in, const int* in_sizes, int n_in,
                              void* d_out, int out_size, void* d_ws, size_t ws_size,
                              hipStream_t stream) {
    const float* x = (const float*)d_in[0];
    const float* p_w = (const float*)d_in[1];
    const float* p_b = (const float*)d_in[2];
    const float* conv_w = (const float*)d_in[3];
    const float* conv_b = (const float*)d_in[4];
    float* out = (float*)d_out;
    char* ws = (char*)d_ws;

    unsigned short* x_t = (unsigned short*)(ws);
    unsigned short* cwtf = (unsigned short*)(ws + CWTF_OFF);
    unsigned short* pwtf = (unsigned short*)(ws + PWTF_OFF);
    unsigned short* zpad = (unsigned short*)(ws + ZPAD_OFF);

    k_prep<<<729, 256, 0, stream>>>(x, (unsigned int*)x_t, conv_w, p_w, cwtf, pwtf, zpad);
    k_fused<<<1024, 512, 0, stream>>>(x_t, cwtf, pwtf, p_b, conv_b, zpad, out);
}

// Round 10
// 49.048 us; speedup vs baseline: 1.0078x; 1.0004x over previous
//
#include <hip/hip_runtime.h>
#include <math.h>

// B=4, C=64, H=W=128, OUTC=64, KS=3, taps N=9, K = 9*64 = 576. All fp16 data, f32 accum.
// ws layout (bytes):
//   x_t   fp16 [4][128][128][64]   @ 0        (8 MB) NHWC
//   cwtf  fp16 [9][2][4][64][8]    @ 8388608  (72 KB) main-conv B-fragments
//   pwtf  fp16 [9][2][2][64][8]    @ 8462336  (36 KB) offset-conv B-fragments (rows>=18 zero)
#define CWTF_OFF 8388608
#define PWTF_OFF (CWTF_OFF + 73728)

typedef __attribute__((ext_vector_type(8))) _Float16 half8;
typedef __attribute__((ext_vector_type(8))) unsigned short ushort8;
typedef __attribute__((ext_vector_type(4))) float f32x4;
typedef __attribute__((ext_vector_type(4))) unsigned int u32x4;

__device__ inline unsigned short f2h(float f) {
    _Float16 h = (_Float16)f; return __builtin_bit_cast(unsigned short, h);
}

// ---------------- prep: x NCHW f32 -> NHWC fp16, + weights -> fragment order ----------------
__global__ __launch_bounds__(256) void k_prep(const float* __restrict__ x,
                                              unsigned int* __restrict__ x_t_u32,
                                              const float* __restrict__ conv_w,
                                              const float* __restrict__ p_w,
                                              unsigned short* __restrict__ cwtf,
                                              unsigned short* __restrict__ pwtf) {
    if (blockIdx.x < 512) {
        __shared__ float t[64][129];
        int b = blockIdx.x >> 7;
        int i = blockIdx.x & 127;
        for (int idx = threadIdx.x; idx < 64 * 128; idx += 256) {
            int c = idx >> 7, j = idx & 127;
            t[c][j] = x[(((size_t)(b * 64 + c) * 128 + i) << 7) + j];
        }
        __syncthreads();
        unsigned int* dst = x_t_u32 + ((size_t)(b * 128 + i)) * 128 * 32;
        for (int idx2 = threadIdx.x; idx2 < 4096; idx2 += 256) {
            int j = idx2 >> 5, c2 = idx2 & 31;
            unsigned int lo = f2h(t[2 * c2][j]);
            unsigned int hi = f2h(t[2 * c2 + 1][j]);
            dst[idx2] = lo | (hi << 16);
        }
    } else {
        int tid = (blockIdx.x - 512) * 256 + threadIdx.x;
        if (tid < 36864) {
            int e = tid & 7, lane = (tid >> 3) & 63, nb = (tid >> 9) & 3, h = (tid >> 11) & 1, n = tid >> 12;
            int o = nb * 16 + (lane & 15);
            int c = h * 32 + ((lane >> 4) << 3) + e;
            cwtf[tid] = f2h(conv_w[(o * 64 + c) * 9 + n]);
        } else if (tid < 36864 + 18432) {
            int t2 = tid - 36864;
            int e = t2 & 7, lane = (t2 >> 3) & 63, nb = (t2 >> 9) & 1, h = (t2 >> 10) & 1, n = t2 >> 11;
            int np = nb * 16 + (lane & 15);
            int c = h * 32 + ((lane >> 4) << 3) + e;
            pwtf[t2] = (np < 18) ? f2h(p_w[(np * 64 + c) * 9 + n]) : (unsigned short)0;
        }
    }
}

// ---------------- fused kernel ----------------
// Block = 64 pixels (b, i, j0..j0+63), 8 waves (512 thr): wave wv = (pg = wv&3, h = wv>>2).
// r6 structure; margin 2 tile + geom-overlays-offs => LDS 52.8 KB => 3 blocks/CU.
// MFMA 16x16x32 f16: A m=lane&15, k=8*(lane>>4)+e; B n=lane&15 same k; D n=lane&15, m=4*(lane>>4)+reg.
#define TROWS 5
#define TCOLS 68
#define TRECS (TROWS * TCOLS)      // 340 records of 128 B (64 ch fp16)
#define TILE_B (TRECS * 128)       // 43520 B
// LDS: tile [0, 43520); geom [9][64][4] u32 (9216 B) overlays offs [64][18] f32 (4608 B) at TILE_B;
// flag at TILE_B + 9216. Total 52752 B. Epilogue ep @ 0 overlays dead tile ([64][65] f32).

__global__ __launch_bounds__(512, 2) void k_fused(const unsigned short* __restrict__ x_t,
                                                  const unsigned short* __restrict__ cwtf,
                                                  const unsigned short* __restrict__ pwtf,
                                                  const float* __restrict__ p_b,
                                                  const float* __restrict__ conv_b,
                                                  float* __restrict__ out) {
    __shared__ __align__(16) unsigned char S[TILE_B + 9216 + 16];
    unsigned char* tile = S;
    float* offs = (float*)(S + TILE_B);
    unsigned char* geomB = S + TILE_B;          // overlays offs after phase 2 reg-stage
    int* flagp = (int*)(S + TILE_B + 9216);
    float* ep = (float*)S;                      // epilogue overlays tile

    int bid = blockIdx.x;
    int b = bid >> 8;
    int i = (bid >> 1) & 127;
    int j0 = (bid & 1) << 6;
    int ib = i - 2, jb = j0 - 2;

    int tid = threadIdx.x;
    int lane = tid & 63;
    int r15 = lane & 15;
    int g = lane >> 4;
    int wv = tid >> 6;
    int pg = wv & 3;
    int h = wv >> 2;
    int pl = pg * 16 + r15;      // this lane's A-row pixel
    int cs = g + (h << 2);       // chunk slot: channels cs*8..cs*8+7

    if (tid == 0) *flagp = 0;

    // ---- stage swizzled x-tile (coalesced global, swizzled ds_write) ----
    for (int u = tid; u < TRECS * 8; u += 512) {
        int rec = u >> 3, chunk = u & 7;
        int trow = rec / TCOLS;
        int tcol = rec - trow * TCOLS;
        int gr = ib + trow, gc = jb + tcol;
        bool v = ((unsigned)gr < 128u) && ((unsigned)gc < 128u);
        int grc = v ? gr : 0, gcc = v ? gc : 0;
        ushort8 val = *(const ushort8*)(x_t + (((size_t)((b * 128 + grc) * 128 + gcc)) << 6) + (chunk << 3));
        if (!v) val = (ushort8)(unsigned short)0;
        *(ushort8*)(tile + rec * 128 + ((chunk ^ (rec & 7)) << 4)) = val;
    }
    __syncthreads();

    // ---- phase 1: offset conv — wave supplies its channel-half's k-block ----
    f32x4 aco0 = (f32x4)0.f, aco1 = (f32x4)0.f;
    for (int n = 0; n < 9; ++n) {
        int du = n / 3 - 1, dv = n % 3 - 1;
        int trec = (du + 2) * TCOLS + (pl + dv + 2);
        int xb = trec & 7;
        half8 a = *(const half8*)(tile + trec * 128 + ((cs ^ xb) << 4));
        const unsigned short* pb = pwtf + (((n * 2 + h) * 2) << 9) + (lane << 3);
        half8 b0 = *(const half8*)pb;
        half8 b1 = *(const half8*)(pb + 512);
        aco0 = __builtin_amdgcn_mfma_f32_16x16x32_f16(a, b0, aco0, 0, 0, 0);
        aco1 = __builtin_amdgcn_mfma_f32_16x16x32_f16(a, b1, aco1, 0, 0, 0);
    }
    // cross-h reduction of offsets: h=0 writes (+bias), h=1 adds
#pragma unroll
    for (int hh = 0; hh < 2; ++hh) {
        if (h == hh) {
#pragma unroll
            for (int nb = 0; nb < 2; ++nb) {
                int np = nb * 16 + r15;
                if (np < 18) {
                    f32x4 a = nb ? aco1 : aco0;
#pragma unroll
                    for (int rr = 0; rr < 4; ++rr) {
                        int pix = pg * 16 + g * 4 + rr;
                        if (hh == 0)
                            offs[pix * 18 + np] = a[rr] + p_b[np];
                        else
                            offs[pix * 18 + np] += a[rr];
                    }
                }
            }
        }
        __syncthreads();
    }

    // ---- phase 2: bilinear geometry (reg-staged; then overlay-write over dead offs) ----
    // item m: pixel p = m&63, tap n = m>>6. Entry u32 = 0x80000000|rx<<23|ry<<16|f16(w), or 0.
    u32x4 gA, gB;
#pragma unroll
    for (int pass = 0; pass < 2; ++pass) {
        int m = tid + pass * 512;
        if (pass == 1 && tid >= 64) break;
        int p = m & 63;
        int n = m >> 6;
        float ox = offs[p * 18 + n];
        float oy = offs[p * 18 + 9 + n];
        float px = ox + (float)(i + 1) + (float)(n / 3 - 1);
        float py = oy + (float)(j0 + p + 1) + (float)(n % 3 - 1);
        float fx = floorf(px), fy = floorf(py);
        float qlx = fminf(fmaxf(fx, 0.f), 129.f);
        float qrx = fminf(fmaxf(fx + 1.f, 0.f), 129.f);
        float qly = fminf(fmaxf(fy, 0.f), 129.f);
        float qry = fminf(fmaxf(fy + 1.f, 0.f), 129.f);
        float pxc = fminf(fmaxf(px, 0.f), 129.f);
        float pyc = fminf(fmaxf(py, 0.f), 129.f);
        float ax = 1.f + qlx - pxc;
        float bx = 1.f - qrx + pxc;
        float ay = 1.f + qly - pyc;
        float by = 1.f - qry + pyc;
        int cx[4], cy[4];
        cx[0] = (int)qlx - 1; cy[0] = (int)qly - 1;
        cx[1] = (int)qrx - 1; cy[1] = (int)qry - 1;
        cx[2] = (int)qlx - 1; cy[2] = (int)qry - 1;
        cx[3] = (int)qrx - 1; cy[3] = (int)qly - 1;
        float cw[4] = {ax * ay, bx * by, ax * by, bx * ay};
        u32x4 pk;
        bool bad = false;
#pragma unroll
        for (int k = 0; k < 4; ++k) {
            bool v = ((unsigned)cx[k] < 128u) && ((unsigned)cy[k] < 128u);
            bool intile = (((unsigned)(cx[k] - ib) < (unsigned)TROWS) &&
                           ((unsigned)(cy[k] - jb) < (unsigned)TCOLS));
            pk[k] = v ? (0x80000000u | ((unsigned)cx[k] << 23) | ((unsigned)cy[k] << 16) | f2h(cw[k])) : 0u;
            bad = bad || (v && !intile);
        }
        if (bad) *flagp = 1;
        if (pass == 0) gA = pk; else gB = pk;
    }
    __syncthreads();  // all offs reads done; safe to overlay
    *(u32x4*)(geomB + (tid << 4)) = gA;
    if (tid < 64) *(u32x4*)(geomB + ((tid + 512) << 4)) = gB;
    __syncthreads();

    // ---- phase 3: main conv — fp16 packed bilinear, wave handles its k-half ----
    f32x4 acc[4];
#pragma unroll
    for (int nb = 0; nb < 4; ++nb) acc[nb] = (f32x4)0.f;
    bool fast = (*flagp == 0);

    if (fast) {
        for (int n = 0; n < 9; ++n) {
            u32x4 gq = *(const u32x4*)(geomB + ((n * 64 + pl) << 4));
            half8 Bf[4];
#pragma unroll
            for (int nb = 0; nb < 4; ++nb)
                Bf[nb] = *(const half8*)(cwtf + ((((n * 2 + h) << 2) + nb) << 9) + (lane << 3));
            half8 av = (half8)(_Float16)0;
#pragma unroll
            for (int k = 0; k < 4; ++k) {
                unsigned int p = gq[k];
                int rx = (int)((p >> 23) & 127u), ry = (int)((p >> 16) & 127u);
                int trec = (rx - ib) * TCOLS + (ry - jb);
                if (p == 0u) trec = 0;
                _Float16 wk = __builtin_bit_cast(_Float16, (unsigned short)(p & 0xFFFFu));
                int xb = trec & 7;
                half8 u = *(const half8*)(tile + trec * 128 + ((cs ^ xb) << 4));
                av += u * wk;   // v_pk_fma_f16
            }
#pragma unroll
            for (int nb = 0; nb < 4; ++nb)
                acc[nb] = __builtin_amdgcn_mfma_f32_16x16x32_f16(av, Bf[nb], acc[nb], 0, 0, 0);
        }
    } else {
        for (int n = 0; n < 9; ++n) {
            u32x4 gq = *(const u32x4*)(geomB + ((n * 64 + pl) << 4));
            half8 Bf[4];
#pragma unroll
            for (int nb = 0; nb < 4; ++nb)
                Bf[nb] = *(const half8*)(cwtf + ((((n * 2 + h) << 2) + nb) << 9) + (lane << 3));
            half8 av = (half8)(_Float16)0;
#pragma unroll
            for (int k = 0; k < 4; ++k) {
                unsigned int p = gq[k];
                int rx = (int)((p >> 23) & 127u), ry = (int)((p >> 16) & 127u);
                size_t base = (p == 0u) ? 0 : (((size_t)((b * 128 + rx) * 128 + ry)) << 6);
                _Float16 wk = __builtin_bit_cast(_Float16, (unsigned short)(p & 0xFFFFu));
                half8 u = *(const half8*)(x_t + base + (cs << 3));
                av += u * wk;
            }
#pragma unroll
            for (int nb = 0; nb < 4; ++nb)
                acc[nb] = __builtin_amdgcn_mfma_f32_16x16x32_f16(av, Bf[nb], acc[nb], 0, 0, 0);
        }
    }
    __syncthreads();  // tile dead; reuse as ep

    // ---- epilogue: cross-h reduction + LDS transpose + coalesced NCHW store ----
#pragma unroll
    for (int hh = 0; hh < 2; ++hh) {
        if (h == hh) {
#pragma unroll
            for (int nb = 0; nb < 4; ++nb) {
                int o = nb * 16 + r15;
#pragma unroll
                for (int rr = 0; rr < 4; ++rr) {
                    int pix = pg * 16 + g * 4 + rr;
                    if (hh == 0)
                        ep[o * 65 + pix] = acc[nb][rr];
                    else
                        ep[o * 65 + pix] += acc[nb][rr];
                }
            }
        }
        __syncthreads();
    }
    for (int t = tid; t < 4096; t += 512) {
        int o = t >> 6;
        int p = t & 63;
        out[(((size_t)(b * 64 + o)) << 14) + (i << 7) + j0 + p] = ep[o * 65 + p] + conv_b[o];
    }
}

extern "C" void kernel_launch(void* const* d_in, const int* in_sizes, int n_in,
                              void* d_out, int out_size, void* d_ws, size_t ws_size,
                              hipStream_t stream) {
    const float* x = (const float*)d_in[0];
    const float* p_w = (const float*)d_in[1];
    const float* p_b = (const float*)d_in[2];
    const float* conv_w = (const float*)d_in[3];
    const float* conv_b = (const float*)d_in[4];
    float* out = (float*)d_out;
    char* ws = (char*)d_ws;

    unsigned short* x_t = (unsigned short*)(ws);
    unsigned short* cwtf = (unsigned short*)(ws + CWTF_OFF);
    unsigned short* pwtf = (unsigned short*)(ws + PWTF_OFF);

    k_prep<<<728, 256, 0, stream>>>(x, (unsigned int*)x_t, conv_w, p_w, cwtf, pwtf);
    k_fused<<<1024, 512, 0, stream>>>(x_t, cwtf, pwtf, p_b, conv_b, out);
}

// Round 11
// 41.229 us; speedup vs baseline: 1.1990x; 1.1896x over previous
//
#include <hip/hip_runtime.h>
#include <math.h>

// B=4, C=64, H=W=128, OUTC=64, KS=3, taps N=9, K = 9*64 = 576. All fp16 data, f32 accum.
// ws layout (bytes):
//   x_t   fp16 [4][128][128][64]   @ 0        (8 MB) NHWC
//   cwtf  fp16 [9][2][4][64][8]    @ 8388608  (72 KB) main-conv B-fragments
//   pwtf  fp16 [9][2][2][64][8]    @ 8462336  (36 KB) offset-conv B-fragments (rows>=18 zero)
#define CWTF_OFF 8388608
#define PWTF_OFF (CWTF_OFF + 73728)

typedef __attribute__((ext_vector_type(8))) _Float16 half8;
typedef __attribute__((ext_vector_type(8))) unsigned short ushort8;
typedef __attribute__((ext_vector_type(4))) float f32x4;
typedef __attribute__((ext_vector_type(4))) unsigned int u32x4;

__device__ inline unsigned short f2h(float f) {
    _Float16 h = (_Float16)f; return __builtin_bit_cast(unsigned short, h);
}

// ---------------- prep: x NCHW f32 -> NHWC fp16, + weights -> fragment order ----------------
__global__ __launch_bounds__(256) void k_prep(const float* __restrict__ x,
                                              unsigned int* __restrict__ x_t_u32,
                                              const float* __restrict__ conv_w,
                                              const float* __restrict__ p_w,
                                              unsigned short* __restrict__ cwtf,
                                              unsigned short* __restrict__ pwtf) {
    if (blockIdx.x < 512) {
        __shared__ float t[64][129];
        int b = blockIdx.x >> 7;
        int i = blockIdx.x & 127;
        for (int idx = threadIdx.x; idx < 64 * 128; idx += 256) {
            int c = idx >> 7, j = idx & 127;
            t[c][j] = x[(((size_t)(b * 64 + c) * 128 + i) << 7) + j];
        }
        __syncthreads();
        unsigned int* dst = x_t_u32 + ((size_t)(b * 128 + i)) * 128 * 32;
        for (int idx2 = threadIdx.x; idx2 < 4096; idx2 += 256) {
            int j = idx2 >> 5, c2 = idx2 & 31;
            unsigned int lo = f2h(t[2 * c2][j]);
            unsigned int hi = f2h(t[2 * c2 + 1][j]);
            dst[idx2] = lo | (hi << 16);
        }
    } else {
        int tid = (blockIdx.x - 512) * 256 + threadIdx.x;
        if (tid < 36864) {
            int e = tid & 7, lane = (tid >> 3) & 63, nb = (tid >> 9) & 3, h = (tid >> 11) & 1, n = tid >> 12;
            int o = nb * 16 + (lane & 15);
            int c = h * 32 + ((lane >> 4) << 3) + e;
            cwtf[tid] = f2h(conv_w[(o * 64 + c) * 9 + n]);
        } else if (tid < 36864 + 18432) {
            int t2 = tid - 36864;
            int e = t2 & 7, lane = (t2 >> 3) & 63, nb = (t2 >> 9) & 1, h = (t2 >> 10) & 1, n = t2 >> 11;
            int np = nb * 16 + (lane & 15);
            int c = h * 32 + ((lane >> 4) << 3) + e;
            pwtf[t2] = (np < 18) ? f2h(p_w[(np * 64 + c) * 9 + n]) : (unsigned short)0;
        }
    }
}

// ---------------- fused kernel (r6 base + XCD swizzle + single-barrier epilogue) ----------------
// Block = 64 pixels (b, i, j0..j0+63), 8 waves (512 thr): wave wv = (pg = wv&3, h = wv>>2).
// Tile margin 3: covers |offset| < 2 (8 sigma) -> slow path statistically never taken.
// MFMA 16x16x32 f16: A m=lane&15, k=8*(lane>>4)+e; B n=lane&15 same k; D n=lane&15, m=4*(lane>>4)+reg.
#define TROWS 7
#define TCOLS 71
#define TRECS (TROWS * TCOLS)      // 497 records of 128 B (64 ch fp16)
#define TILE_B (TRECS * 128)       // 63616 B
#define OFF_OFFS TILE_B            // 4608 B  [64][18] f32
#define OFF_GEOM (TILE_B + 4608)   // 9216 B  [9][64][4] packed u32
#define OFF_FLAG (TILE_B + 4608 + 9216)
// Epilogue: ep0 @ 0, ep1 @ 16640 ([64][65] f32 each) overlay the dead tile.

__global__ __launch_bounds__(512, 2) void k_fused(const unsigned short* __restrict__ x_t,
                                                  const unsigned short* __restrict__ cwtf,
                                                  const unsigned short* __restrict__ pwtf,
                                                  const float* __restrict__ p_b,
                                                  const float* __restrict__ conv_b,
                                                  float* __restrict__ out) {
    __shared__ __align__(16) unsigned char S[TILE_B + 4608 + 9216 + 16];
    unsigned char* tile = S;
    float* offs = (float*)(S + OFF_OFFS);
    unsigned char* geomB = S + OFF_GEOM;
    int* flagp = (int*)(S + OFF_FLAG);

    int bid0 = blockIdx.x;
    int bid = (bid0 & 7) * 128 + (bid0 >> 3);  // chunked XCD swizzle (1024 % 8 == 0)
    int b = bid >> 8;
    int i = (bid >> 1) & 127;
    int j0 = (bid & 1) << 6;
    int ib = i - 3, jb = j0 - 3;

    int tid = threadIdx.x;
    int lane = tid & 63;
    int r15 = lane & 15;
    int g = lane >> 4;
    int wv = tid >> 6;
    int pg = wv & 3;
    int h = wv >> 2;
    int pl = pg * 16 + r15;      // this lane's A-row pixel
    int cs = g + (h << 2);       // chunk slot: channels cs*8..cs*8+7

    if (tid == 0) *flagp = 0;

    // ---- stage swizzled x-tile (coalesced global, swizzled ds_write) ----
    for (int u = tid; u < TRECS * 8; u += 512) {
        int rec = u >> 3, chunk = u & 7;
        int trow = rec / TCOLS;
        int tcol = rec - trow * TCOLS;
        int gr = ib + trow, gc = jb + tcol;
        bool v = ((unsigned)gr < 128u) && ((unsigned)gc < 128u);
        int grc = v ? gr : 0, gcc = v ? gc : 0;
        ushort8 val = *(const ushort8*)(x_t + (((size_t)((b * 128 + grc) * 128 + gcc)) << 6) + (chunk << 3));
        if (!v) val = (ushort8)(unsigned short)0;
        *(ushort8*)(tile + rec * 128 + ((chunk ^ (rec & 7)) << 4)) = val;
    }
    __syncthreads();

    // ---- phase 1: offset conv — wave supplies its channel-half's k-block ----
    f32x4 aco0 = (f32x4)0.f, aco1 = (f32x4)0.f;
    for (int n = 0; n < 9; ++n) {
        int du = n / 3 - 1, dv = n % 3 - 1;
        int trec = (du + 3) * TCOLS + (pl + dv + 3);
        int xb = trec & 7;
        half8 a = *(const half8*)(tile + trec * 128 + ((cs ^ xb) << 4));
        const unsigned short* pb = pwtf + (((n * 2 + h) * 2) << 9) + (lane << 3);
        half8 b0 = *(const half8*)pb;
        half8 b1 = *(const half8*)(pb + 512);
        aco0 = __builtin_amdgcn_mfma_f32_16x16x32_f16(a, b0, aco0, 0, 0, 0);
        aco1 = __builtin_amdgcn_mfma_f32_16x16x32_f16(a, b1, aco1, 0, 0, 0);
    }
    // cross-h reduction of offsets: h=0 writes (+bias), h=1 adds
#pragma unroll
    for (int hh = 0; hh < 2; ++hh) {
        if (h == hh) {
#pragma unroll
            for (int nb = 0; nb < 2; ++nb) {
                int np = nb * 16 + r15;
                if (np < 18) {
                    f32x4 a = nb ? aco1 : aco0;
#pragma unroll
                    for (int rr = 0; rr < 4; ++rr) {
                        int pix = pg * 16 + g * 4 + rr;
                        if (hh == 0)
                            offs[pix * 18 + np] = a[rr] + p_b[np];
                        else
                            offs[pix * 18 + np] += a[rr];
                    }
                }
            }
        }
        __syncthreads();
    }

    // ---- phase 2: bilinear geometry, packed (validbit|rx|ry|f16 w) ----
    for (int t = tid; t < 576; t += 512) {
        int p = t / 9;
        int n = t - p * 9;
        float ox = offs[p * 18 + n];
        float oy = offs[p * 18 + 9 + n];
        float px = ox + (float)(i + 1) + (float)(n / 3 - 1);
        float py = oy + (float)(j0 + p + 1) + (float)(n % 3 - 1);
        float fx = floorf(px), fy = floorf(py);
        float qlx = fminf(fmaxf(fx, 0.f), 129.f);
        float qrx = fminf(fmaxf(fx + 1.f, 0.f), 129.f);
        float qly = fminf(fmaxf(fy, 0.f), 129.f);
        float qry = fminf(fmaxf(fy + 1.f, 0.f), 129.f);
        float pxc = fminf(fmaxf(px, 0.f), 129.f);
        float pyc = fminf(fmaxf(py, 0.f), 129.f);
        float ax = 1.f + qlx - pxc;
        float bx = 1.f - qrx + pxc;
        float ay = 1.f + qly - pyc;
        float by = 1.f - qry + pyc;
        int rlx = (int)qlx - 1, rrx = (int)qrx - 1;
        int rly = (int)qly - 1, rry = (int)qry - 1;
        bool bad = false;
        unsigned int pk[4];
        int cx[4] = {rlx, rrx, rlx, rrx};
        int cy[4] = {rly, rry, rry, rly};
        float cw[4] = {ax * ay, bx * by, ax * by, bx * ay};
#pragma unroll
        for (int k = 0; k < 4; ++k) {
            bool v = ((unsigned)cx[k] < 128u) && ((unsigned)cy[k] < 128u);
            bool intile = (((unsigned)(cx[k] - ib) < (unsigned)TROWS) &&
                           ((unsigned)(cy[k] - jb) < (unsigned)TCOLS));
            pk[k] = v ? (0x80000000u | ((unsigned)cx[k] << 23) | ((unsigned)cy[k] << 16) | f2h(cw[k])) : 0u;
            bad = bad || (v && !intile);
        }
        *(u32x4*)(geomB + ((n * 64 + p) << 4)) = (u32x4){pk[0], pk[1], pk[2], pk[3]};
        if (bad) *flagp = 1;
    }
    __syncthreads();

    // ---- phase 3: main conv — fp16 packed bilinear, wave handles its k-half ----
    f32x4 acc[4];
#pragma unroll
    for (int nb = 0; nb < 4; ++nb) acc[nb] = (f32x4)0.f;
    bool fast = (*flagp == 0);

    if (fast) {
        for (int n = 0; n < 9; ++n) {
            u32x4 gq = *(const u32x4*)(geomB + ((n * 64 + pl) << 4));
            half8 Bf[4];
#pragma unroll
            for (int nb = 0; nb < 4; ++nb)
                Bf[nb] = *(const half8*)(cwtf + ((((n * 2 + h) << 2) + nb) << 9) + (lane << 3));
            half8 av = (half8)(_Float16)0;
#pragma unroll
            for (int k = 0; k < 4; ++k) {
                unsigned int p = gq[k];
                int rx = (int)((p >> 23) & 127u), ry = (int)((p >> 16) & 127u);
                int trec = (rx - ib) * TCOLS + (ry - jb);
                if (p == 0u) trec = 0;
                _Float16 wk = __builtin_bit_cast(_Float16, (unsigned short)(p & 0xFFFFu));
                int xb = trec & 7;
                half8 u = *(const half8*)(tile + trec * 128 + ((cs ^ xb) << 4));
                av += u * wk;   // v_pk_fma_f16
            }
#pragma unroll
            for (int nb = 0; nb < 4; ++nb)
                acc[nb] = __builtin_amdgcn_mfma_f32_16x16x32_f16(av, Bf[nb], acc[nb], 0, 0, 0);
        }
    } else {
        for (int n = 0; n < 9; ++n) {
            u32x4 gq = *(const u32x4*)(geomB + ((n * 64 + pl) << 4));
            half8 Bf[4];
#pragma unroll
            for (int nb = 0; nb < 4; ++nb)
                Bf[nb] = *(const half8*)(cwtf + ((((n * 2 + h) << 2) + nb) << 9) + (lane << 3));
            half8 av = (half8)(_Float16)0;
#pragma unroll
            for (int k = 0; k < 4; ++k) {
                unsigned int p = gq[k];
                int rx = (int)((p >> 23) & 127u), ry = (int)((p >> 16) & 127u);
                size_t base = (p == 0u) ? 0 : (((size_t)((b * 128 + rx) * 128 + ry)) << 6);
                _Float16 wk = __builtin_bit_cast(_Float16, (unsigned short)(p & 0xFFFFu));
                half8 u = *(const half8*)(x_t + base + (cs << 3));
                av += u * wk;
            }
#pragma unroll
            for (int nb = 0; nb < 4; ++nb)
                acc[nb] = __builtin_amdgcn_mfma_f32_16x16x32_f16(av, Bf[nb], acc[nb], 0, 0, 0);
        }
    }
    __syncthreads();  // tile dead; reuse as ep0/ep1

    // ---- epilogue: disjoint per-half regions, ONE barrier, summed at store ----
    {
        float* epH = (float*)(S + (h ? 16640 : 0));
#pragma unroll
        for (int nb = 0; nb < 4; ++nb) {
            int o = nb * 16 + r15;
#pragma unroll
            for (int rr = 0; rr < 4; ++rr) {
                int pix = pg * 16 + g * 4 + rr;
                epH[o * 65 + pix] = acc[nb][rr];
            }
        }
    }
    __syncthreads();
    {
        float* e0 = (float*)S;
        float* e1 = (float*)(S + 16640);
        for (int t = tid; t < 4096; t += 512) {
            int o = t >> 6;
            int p = t & 63;
            out[(((size_t)(b * 64 + o)) << 14) + (i << 7) + j0 + p] =
                e0[o * 65 + p] + e1[o * 65 + p] + conv_b[o];
        }
    }
}

extern "C" void kernel_launch(void* const* d_in, const int* in_sizes, int n_in,
                              void* d_out, int out_size, void* d_ws, size_t ws_size,
                              hipStream_t stream) {
    const float* x = (const float*)d_in[0];
    const float* p_w = (const float*)d_in[1];
    const float* p_b = (const float*)d_in[2];
    const float* conv_w = (const float*)d_in[3];
    const float* conv_b = (const float*)d_in[4];
    float* out = (float*)d_out;
    char* ws = (char*)d_ws;

    unsigned short* x_t = (unsigned short*)(ws);
    unsigned short* cwtf = (unsigned short*)(ws + CWTF_OFF);
    unsigned short* pwtf = (unsigned short*)(ws + PWTF_OFF);

    k_prep<<<728, 256, 0, stream>>>(x, (unsigned int*)x_t, conv_w, p_w, cwtf, pwtf);
    k_fused<<<1024, 512, 0, stream>>>(x_t, cwtf, pwtf, p_b, conv_b, out);
}